// Round 3
// baseline (635.374 us; speedup 1.0000x reference)
//
#include <hip/hip_runtime.h>
#include <cstdint>

typedef unsigned short u16;
typedef __attribute__((ext_vector_type(8))) short s8v;   // 8 bf16 = one MFMA operand frag
typedef __attribute__((ext_vector_type(4))) float f4v;   // MFMA accumulator / vec loads

__device__ __forceinline__ float bf2f(u16 b) {
  unsigned int u = ((unsigned int)b) << 16;
  float f;
  __builtin_memcpy(&f, &u, 4);
  return f;
}
__device__ __forceinline__ u16 f2bf(float f) {
  unsigned int u;
  __builtin_memcpy(&u, &f, 4);
  u += 0x7fffu + ((u >> 16) & 1u);   // RNE (finite inputs only)
  return (u16)(u >> 16);
}

#define BM 128
#define BN 128
#define BK 32
#define LSTR 40   // LDS row stride (bf16 elems); 80B rows stay 16B-aligned, break pow2 banking

// ---------------- dtype detector ----------------
// flag=1 : fp32 storage.  flag=0 : bf16 storage.
__global__ __launch_bounds__(256)
void detect_dtype(const u16* __restrict__ q, int* __restrict__ flag)
{
  __shared__ int cbig, czero;
  if (threadIdx.x == 0) { cbig = 0; czero = 0; }
  __syncthreads();
  int b = 0, z = 0;
  for (int i = threadIdx.x; i < 4096; i += 256) {
    float v = bf2f(q[i]);
    if (!(fabsf(v) < 1e4f)) b++;            // counts NaN/Inf too
    if ((i & 1) == 0 && q[i] == 0) z++;     // little-endian low half of an fp32
  }
  atomicAdd(&cbig, b);
  atomicAdd(&czero, z);
  __syncthreads();
  if (threadIdx.x == 0) *flag = (cbig > 64 || czero > 1600) ? 1 : 0;
}

// ---------------- transpose (flag-aware input) ----------------
// out[c][r] = in[r][c].  AMODE: 0 = input dtype per flag, 2 = input bf16.
// OUT32: write fp32 (full precision) else bf16.
template<int AMODE, bool OUT32>
__global__ __launch_bounds__(256)
void transpose_any(const int* __restrict__ flg, const void* __restrict__ in_v,
                   void* __restrict__ out_v, int R, int C, long sIn, long sOut)
{
  __shared__ float tile[32][33];
  const bool i32 = (AMODE == 0) && (*flg != 0);
  const u16*   in16 = (const u16*)in_v + (long)blockIdx.z * sIn;
  const float* in32 = (const float*)in_v + (long)blockIdx.z * sIn;
  const int c0 = blockIdx.x * 32, r0 = blockIdx.y * 32;
  const int tx = threadIdx.x, ty = threadIdx.y;   // block (32,8)
  for (int i = ty; i < 32; i += 8) {
    const long idx = (long)(r0 + i) * C + c0 + tx;
    tile[i][tx] = i32 ? in32[idx] : bf2f(in16[idx]);
  }
  __syncthreads();
  for (int i = ty; i < 32; i += 8) {
    const long idx = (long)blockIdx.z * sOut + (long)(c0 + i) * R + r0 + tx;
    if constexpr (OUT32) ((float*)out_v)[idx] = tile[tx][i];
    else                 ((u16*)out_v)[idx]   = f2bf(tile[tx][i]);
  }
}

// ---------------- plain bf16 NT GEMM ----------------
// C[m][n] = sum_k A[m][k]*Bt[n][k] (+bias[n]).  Bt bf16.
// AMODE: 0 = A per flag, 1 = A fp32, 2 = A bf16.
// OUT_MODE: 0 = per flag (fp32 if flag else bf16), 1 = fp32, 2 = bf16.
template<int AMODE, int OUT_MODE, bool HAS_BIAS>
__global__ __launch_bounds__(256)
void gemm_nt(const int* __restrict__ flg, const void* __restrict__ Av,
             const u16* __restrict__ Bt, const void* __restrict__ bias,
             void* __restrict__ Cv, int M, int N, int K,
             long sA, long sB, long sC)
{
  __shared__ short As[BM * LSTR];
  __shared__ short Bs[BN * LSTR];

  const int f_in = *flg;
  const bool a32 = (AMODE == 1) || (AMODE == 0 && f_in != 0);
  const bool o32 = (OUT_MODE == 1) || (OUT_MODE == 0 && f_in != 0);

  const int tid  = threadIdx.x;
  const int lane = tid & 63;
  const int wave = tid >> 6;
  const int wm = wave >> 1;
  const int wn = wave & 1;
  const int m0 = blockIdx.y * BM;
  const int n0 = blockIdx.x * BN;
  const long z = blockIdx.z;

  const u16*   A16 = (const u16*)Av + z * sA;
  const float* A32 = (const float*)Av + z * sA;
  const u16*   Bp  = Bt + z * sB;

  const int srow = tid >> 1;             // 0..127
  const int scol = (tid & 1) * 16;       // 0 / 16

  f4v acc[4][4];
#pragma unroll
  for (int i = 0; i < 4; ++i)
#pragma unroll
    for (int j = 0; j < 4; ++j) acc[i][j] = (f4v){0.f, 0.f, 0.f, 0.f};

  const int fr = lane & 15;
  const int fk = (lane >> 4) * 8;

  for (int kt = 0; kt < K; kt += BK) {
    if (a32) {
      const float* src = A32 + (long)(m0 + srow) * K + kt + scol;
      f4v f0 = *(const f4v*)(src);
      f4v f1 = *(const f4v*)(src + 4);
      f4v f2 = *(const f4v*)(src + 8);
      f4v f3 = *(const f4v*)(src + 12);
      s8v p0, p1;
#pragma unroll
      for (int j = 0; j < 4; ++j) {
        p0[j]     = (short)f2bf(f0[j]);
        p0[4 + j] = (short)f2bf(f1[j]);
        p1[j]     = (short)f2bf(f2[j]);
        p1[4 + j] = (short)f2bf(f3[j]);
      }
      *(s8v*)&As[srow * LSTR + scol]     = p0;
      *(s8v*)&As[srow * LSTR + scol + 8] = p1;
    } else {
      const short* src = (const short*)A16 + (long)(m0 + srow) * K + kt + scol;
      *(s8v*)&As[srow * LSTR + scol]     = *(const s8v*)(src);
      *(s8v*)&As[srow * LSTR + scol + 8] = *(const s8v*)(src + 8);
    }
    {
      const short* src = (const short*)Bp + (long)(n0 + srow) * K + kt + scol;
      *(s8v*)&Bs[srow * LSTR + scol]     = *(const s8v*)(src);
      *(s8v*)&Bs[srow * LSTR + scol + 8] = *(const s8v*)(src + 8);
    }
    __syncthreads();

    s8v af[4], bf[4];
#pragma unroll
    for (int mi = 0; mi < 4; ++mi)
      af[mi] = *(const s8v*)&As[(wm * 64 + mi * 16 + fr) * LSTR + fk];
#pragma unroll
    for (int ni = 0; ni < 4; ++ni)
      bf[ni] = *(const s8v*)&Bs[(wn * 64 + ni * 16 + fr) * LSTR + fk];
#pragma unroll
    for (int mi = 0; mi < 4; ++mi)
#pragma unroll
      for (int ni = 0; ni < 4; ++ni)
        acc[mi][ni] = __builtin_amdgcn_mfma_f32_16x16x32_bf16(af[mi], bf[ni], acc[mi][ni], 0, 0, 0);
    __syncthreads();
  }

  // epilogue: C/D layout col=lane&15, row=(lane>>4)*4+reg (m89-verified)
  const int cr = (lane >> 4) * 4;
  const int cc = lane & 15;
#pragma unroll
  for (int ni = 0; ni < 4; ++ni) {
    const int gcol = n0 + wn * 64 + ni * 16 + cc;
    float bv = 0.f;
    if (HAS_BIAS)
      bv = (f_in != 0) ? ((const float*)bias)[gcol] : bf2f(((const u16*)bias)[gcol]);
#pragma unroll
    for (int mi = 0; mi < 4; ++mi)
#pragma unroll
      for (int r = 0; r < 4; ++r) {
        const long grow = (long)(m0 + wm * 64 + mi * 16 + cr + r);
        const float val = acc[mi][ni][r] + bv;
        const long idx = z * sC + grow * N + gcol;
        if (o32) ((float*)Cv)[idx] = val;
        else     ((u16*)Cv)[idx]   = f2bf(val);
      }
  }
}

// ---------------- split-precision NT GEMM (~17-bit mantissa) ----------------
// C(fp32) = A*Bt^T + bias.  Bt is fp32 [N][K] (ours).  A: AMODE 0 = per flag, 1 = fp32.
// hi/lo bf16 decomposition, 3 MFMAs: hh + hl + lh.
template<int AMODE, bool HAS_BIAS>
__global__ __launch_bounds__(256)
void gemm_split(const int* __restrict__ flg, const void* __restrict__ Av,
                const float* __restrict__ Bt, const void* __restrict__ bias,
                float* __restrict__ C, int M, int N, int K,
                long sA, long sB, long sC)
{
  __shared__ short Ah[BM * LSTR];
  __shared__ short Al[BM * LSTR];
  __shared__ short Bh[BN * LSTR];
  __shared__ short Bl[BN * LSTR];

  const int f_in = *flg;
  const bool a32 = (AMODE == 1) || (f_in != 0);

  const int tid  = threadIdx.x;
  const int lane = tid & 63;
  const int wave = tid >> 6;
  const int wm = wave >> 1;
  const int wn = wave & 1;
  const int m0 = blockIdx.y * BM;
  const int n0 = blockIdx.x * BN;
  const long z = blockIdx.z;

  const u16*   A16 = (const u16*)Av + z * sA;
  const float* A32 = (const float*)Av + z * sA;
  const float* Bp  = Bt + z * sB;

  const int srow = tid >> 1;
  const int scol = (tid & 1) * 16;

  f4v acc[4][4];
#pragma unroll
  for (int i = 0; i < 4; ++i)
#pragma unroll
    for (int j = 0; j < 4; ++j) acc[i][j] = (f4v){0.f, 0.f, 0.f, 0.f};

  const int fr = lane & 15;
  const int fk = (lane >> 4) * 8;

  for (int kt = 0; kt < K; kt += BK) {
    // ---- A tile ----
    if (a32) {
      const float* src = A32 + (long)(m0 + srow) * K + kt + scol;
      f4v f0 = *(const f4v*)(src);
      f4v f1 = *(const f4v*)(src + 4);
      f4v f2 = *(const f4v*)(src + 8);
      f4v f3 = *(const f4v*)(src + 12);
      s8v h0, h1, l0, l1;
#pragma unroll
      for (int j = 0; j < 4; ++j) {
        u16 h;
        h = f2bf(f0[j]); h0[j]   = (short)h; l0[j]   = (short)f2bf(f0[j] - bf2f(h));
        h = f2bf(f1[j]); h0[4+j] = (short)h; l0[4+j] = (short)f2bf(f1[j] - bf2f(h));
        h = f2bf(f2[j]); h1[j]   = (short)h; l1[j]   = (short)f2bf(f2[j] - bf2f(h));
        h = f2bf(f3[j]); h1[4+j] = (short)h; l1[4+j] = (short)f2bf(f3[j] - bf2f(h));
      }
      *(s8v*)&Ah[srow * LSTR + scol]     = h0;
      *(s8v*)&Ah[srow * LSTR + scol + 8] = h1;
      *(s8v*)&Al[srow * LSTR + scol]     = l0;
      *(s8v*)&Al[srow * LSTR + scol + 8] = l1;
    } else {
      const short* src = (const short*)A16 + (long)(m0 + srow) * K + kt + scol;
      s8v zv;
#pragma unroll
      for (int j = 0; j < 8; ++j) zv[j] = 0;
      *(s8v*)&Ah[srow * LSTR + scol]     = *(const s8v*)(src);
      *(s8v*)&Ah[srow * LSTR + scol + 8] = *(const s8v*)(src + 8);
      *(s8v*)&Al[srow * LSTR + scol]     = zv;
      *(s8v*)&Al[srow * LSTR + scol + 8] = zv;
    }
    // ---- B tile (always fp32) ----
    {
      const float* src = Bp + (long)(n0 + srow) * K + kt + scol;
      f4v f0 = *(const f4v*)(src);
      f4v f1 = *(const f4v*)(src + 4);
      f4v f2 = *(const f4v*)(src + 8);
      f4v f3 = *(const f4v*)(src + 12);
      s8v h0, h1, l0, l1;
#pragma unroll
      for (int j = 0; j < 4; ++j) {
        u16 h;
        h = f2bf(f0[j]); h0[j]   = (short)h; l0[j]   = (short)f2bf(f0[j] - bf2f(h));
        h = f2bf(f1[j]); h0[4+j] = (short)h; l0[4+j] = (short)f2bf(f1[j] - bf2f(h));
        h = f2bf(f2[j]); h1[j]   = (short)h; l1[j]   = (short)f2bf(f2[j] - bf2f(h));
        h = f2bf(f3[j]); h1[4+j] = (short)h; l1[4+j] = (short)f2bf(f3[j] - bf2f(h));
      }
      *(s8v*)&Bh[srow * LSTR + scol]     = h0;
      *(s8v*)&Bh[srow * LSTR + scol + 8] = h1;
      *(s8v*)&Bl[srow * LSTR + scol]     = l0;
      *(s8v*)&Bl[srow * LSTR + scol + 8] = l1;
    }
    __syncthreads();

    s8v ah[4], al[4], bh[4], bl[4];
#pragma unroll
    for (int mi = 0; mi < 4; ++mi) {
      const int row = (wm * 64 + mi * 16 + fr) * LSTR + fk;
      ah[mi] = *(const s8v*)&Ah[row];
      al[mi] = *(const s8v*)&Al[row];
    }
#pragma unroll
    for (int ni = 0; ni < 4; ++ni) {
      const int row = (wn * 64 + ni * 16 + fr) * LSTR + fk;
      bh[ni] = *(const s8v*)&Bh[row];
      bl[ni] = *(const s8v*)&Bl[row];
    }
#pragma unroll
    for (int mi = 0; mi < 4; ++mi)
#pragma unroll
      for (int ni = 0; ni < 4; ++ni) {
        acc[mi][ni] = __builtin_amdgcn_mfma_f32_16x16x32_bf16(ah[mi], bh[ni], acc[mi][ni], 0, 0, 0);
        acc[mi][ni] = __builtin_amdgcn_mfma_f32_16x16x32_bf16(ah[mi], bl[ni], acc[mi][ni], 0, 0, 0);
        acc[mi][ni] = __builtin_amdgcn_mfma_f32_16x16x32_bf16(al[mi], bh[ni], acc[mi][ni], 0, 0, 0);
      }
    __syncthreads();
  }

  const int cr = (lane >> 4) * 4;
  const int cc = lane & 15;
#pragma unroll
  for (int ni = 0; ni < 4; ++ni) {
    const int gcol = n0 + wn * 64 + ni * 16 + cc;
    float bv = 0.f;
    if (HAS_BIAS)
      bv = (f_in != 0) ? ((const float*)bias)[gcol] : bf2f(((const u16*)bias)[gcol]);
#pragma unroll
    for (int mi = 0; mi < 4; ++mi)
#pragma unroll
      for (int r = 0; r < 4; ++r) {
        const long grow = (long)(m0 + wm * 64 + mi * 16 + cr + r);
        C[z * sC + grow * N + gcol] = acc[mi][ni][r] + bv;
      }
  }
}

// ---------------- row softmax, fp32, N=2048, one 256-thread block per row ----------------
__global__ __launch_bounds__(256)
void softmax_rows(float* __restrict__ S, int N)
{
  float* row = S + (long)blockIdx.x * N;
  const int t = threadIdx.x;
  f4v v0 = *(f4v*)(row + t * 8);
  f4v v1 = *(f4v*)(row + t * 8 + 4);

  float m = v0[0];
#pragma unroll
  for (int j = 1; j < 4; ++j) m = fmaxf(m, v0[j]);
#pragma unroll
  for (int j = 0; j < 4; ++j) m = fmaxf(m, v1[j]);
  for (int off = 32; off > 0; off >>= 1) m = fmaxf(m, __shfl_down(m, off, 64));

  __shared__ float redm[4], reds[4];
  if ((t & 63) == 0) redm[t >> 6] = m;
  __syncthreads();
  m = fmaxf(fmaxf(redm[0], redm[1]), fmaxf(redm[2], redm[3]));

  float s = 0.f;
#pragma unroll
  for (int j = 0; j < 4; ++j) { v0[j] = __expf(v0[j] - m); s += v0[j]; }
#pragma unroll
  for (int j = 0; j < 4; ++j) { v1[j] = __expf(v1[j] - m); s += v1[j]; }
  for (int off = 32; off > 0; off >>= 1) s += __shfl_down(s, off, 64);
  if ((t & 63) == 0) reds[t >> 6] = s;
  __syncthreads();
  s = reds[0] + reds[1] + reds[2] + reds[3];

  const float inv = 1.f / s;
#pragma unroll
  for (int j = 0; j < 4; ++j) { v0[j] *= inv; v1[j] *= inv; }
  *(f4v*)(row + t * 8)     = v0;
  *(f4v*)(row + t * 8 + 4) = v1;
}

extern "C" void kernel_launch(void* const* d_in, const int* in_sizes, int n_in,
                              void* d_out, int out_size, void* d_ws, size_t ws_size,
                              hipStream_t stream)
{
  const void* query = d_in[0];
  const void* kv    = d_in[1];
  const void* Wq    = d_in[2];
  const void* bq    = d_in[3];
  const void* Wk    = d_in[4];
  const void* bk    = d_in[5];
  const void* Wv    = d_in[6];
  const void* bv    = d_in[7];
  const void* Wo    = d_in[8];
  const void* bo    = d_in[9];

  const int Bn = 4, S = 2048, D = 1024;
  const int MS = Bn * S;                       // 8192
  const size_t MB = 1024 * 1024;

  char* ws = (char*)d_ws;
  int*   flg   = (int*)(ws + 0);
  float* WqT32 = (float*)(ws + 1 * MB);        // [D][D] fp32, 4MB
  float* WkT32 = (float*)(ws + 5 * MB);        // 4MB
  u16*   WvT16 = (u16*)(ws + 9 * MB);          // [D][D] bf16, 2MB
  u16*   WoT16 = (u16*)(ws + 11 * MB);         // 2MB
  float* Qf    = (float*)(ws + 13 * MB);       // [B][S][D] fp32, 32MB
  float* Kf    = (float*)(ws + 45 * MB);       // 32MB
  u16*   Vb    = (u16*)(ws + 77 * MB);         // [B][S][D] bf16, 16MB
  u16*   Cx    = (u16*)(ws + 77 * MB);         //   ctx overlays Vb (dead after V-transpose)
  u16*   Vt    = (u16*)(ws + 93 * MB);         // [B][D][S] bf16, 16MB
  float* Sc    = (float*)(ws + 109 * MB);      // scores fp32, 16MB/batch

  detect_dtype<<<1, 256, 0, stream>>>((const u16*)query, flg);

  dim3 tb(32, 8);
  // W^T: Wq,Wk at full fp32 precision (split-GEMM operands); Wv,Wo bf16.
  transpose_any<0, true ><<<dim3(D / 32, D / 32, 1), tb, 0, stream>>>(flg, Wq, WqT32, D, D, 0L, 0L);
  transpose_any<0, true ><<<dim3(D / 32, D / 32, 1), tb, 0, stream>>>(flg, Wk, WkT32, D, D, 0L, 0L);
  transpose_any<0, false><<<dim3(D / 32, D / 32, 1), tb, 0, stream>>>(flg, Wv, WvT16, D, D, 0L, 0L);
  transpose_any<0, false><<<dim3(D / 32, D / 32, 1), tb, 0, stream>>>(flg, Wo, WoT16, D, D, 0L, 0L);

  // Q,K projections in split precision -> fp32 (softmax argmax sensitivity); V plain bf16.
  gemm_split<0, true><<<dim3(D / BN, MS / BM, 1), 256, 0, stream>>>(
      flg, query, WqT32, bq, Qf, MS, D, D, 0L, 0L, 0L);
  gemm_split<0, true><<<dim3(D / BN, MS / BM, 1), 256, 0, stream>>>(
      flg, kv, WkT32, bk, Kf, MS, D, D, 0L, 0L, 0L);
  gemm_nt<0, 2, true><<<dim3(D / BN, MS / BM, 1), 256, 0, stream>>>(
      flg, kv, WvT16, bv, Vb, MS, D, D, 0L, 0L, 0L);

  // V^T per batch: [D][S] bf16
  transpose_any<2, false><<<dim3(D / 32, S / 32, Bn), tb, 0, stream>>>(
      flg, Vb, Vt, S, D, (long)S * D, (long)D * S);

  // attention
  const size_t need_full = 109 * MB + (size_t)Bn * S * S * sizeof(float);
  const int zc = (ws_size >= need_full) ? Bn : 1;
  for (int b0 = 0; b0 < Bn; b0 += zc) {
    gemm_split<1, false><<<dim3(S / BN, S / BM, zc), 256, 0, stream>>>(
        flg, Qf + (long)b0 * S * D, WkT32 /*unused pattern*/ == nullptr ? nullptr : Kf + (long)b0 * S * D,
        nullptr, Sc, S, S, D, (long)S * D, (long)S * D, (long)S * S);
    softmax_rows<<<dim3(zc * S), 256, 0, stream>>>(Sc, S);
    gemm_nt<1, 2, false><<<dim3(D / BN, S / BM, zc), 256, 0, stream>>>(
        flg, Sc, Vt + (long)b0 * D * S, nullptr, Cx + (long)b0 * S * D,
        S, D, S, (long)S * S, (long)D * S, (long)S * D);
  }

  // output projection -> d_out, dtype follows flag (fp32 expected)
  gemm_nt<2, 0, true><<<dim3(D / BN, MS / BM, 1), 256, 0, stream>>>(
      flg, Cx, WoT16, bo, d_out, MS, D, D, 0L, 0L, 0L);
}

// Round 4
// 544.144 us; speedup vs baseline: 1.1677x; 1.1677x over previous
//
#include <hip/hip_runtime.h>
#include <cstdint>

typedef unsigned short u16;
typedef __attribute__((ext_vector_type(8))) short s8v;   // 8 bf16 = one MFMA operand frag
typedef __attribute__((ext_vector_type(4))) float f4v;   // MFMA accumulator / vec loads

__device__ __forceinline__ float bf2f(u16 b) {
  unsigned int u = ((unsigned int)b) << 16;
  float f;
  __builtin_memcpy(&f, &u, 4);
  return f;
}
__device__ __forceinline__ u16 f2bf(float f) {
  unsigned int u;
  __builtin_memcpy(&u, &f, 4);
  u += 0x7fffu + ((u >> 16) & 1u);   // RNE (finite inputs only)
  return (u16)(u >> 16);
}

// async global->LDS, 16B per lane; LDS dest = wave-uniform base + lane*16
__device__ __forceinline__ void glds16(const void* g, void* l) {
  __builtin_amdgcn_global_load_lds(
      (const __attribute__((address_space(1))) unsigned int*)g,
      (__attribute__((address_space(3))) unsigned int*)l, 16, 0, 0);
}

#define BM 128
#define BN 128
#define BK 32

// ---------------- dtype detector (flag=1: fp32 storage, 0: bf16) ----------------
__global__ __launch_bounds__(256)
void detect_dtype(const u16* __restrict__ q, int* __restrict__ flag)
{
  __shared__ int cbig, czero;
  if (threadIdx.x == 0) { cbig = 0; czero = 0; }
  __syncthreads();
  int b = 0, z = 0;
  for (int i = threadIdx.x; i < 4096; i += 256) {
    float v = bf2f(q[i]);
    if (!(fabsf(v) < 1e4f)) b++;
    if ((i & 1) == 0 && q[i] == 0) z++;
  }
  atomicAdd(&cbig, b);
  atomicAdd(&czero, z);
  __syncthreads();
  if (threadIdx.x == 0) *flag = (cbig > 64 || czero > 1600) ? 1 : 0;
}

// ---------------- input -> hi/lo bf16 planes ----------------
__global__ __launch_bounds__(256)
void convert_hl(const int* __restrict__ flg, const void* __restrict__ in,
                u16* __restrict__ hi, u16* __restrict__ lo, long n)
{
  const long i = ((long)blockIdx.x * 256 + threadIdx.x) * 8;
  if (i >= n) return;
  s8v h, l;
  if (*flg != 0) {
    const float* p = (const float*)in + i;
    f4v f0 = *(const f4v*)p;
    f4v f1 = *(const f4v*)(p + 4);
#pragma unroll
    for (int j = 0; j < 4; ++j) {
      u16 hh;
      hh = f2bf(f0[j]); h[j]     = (short)hh; l[j]     = (short)f2bf(f0[j] - bf2f(hh));
      hh = f2bf(f1[j]); h[4 + j] = (short)hh; l[4 + j] = (short)f2bf(f1[j] - bf2f(hh));
    }
  } else {
    h = *(const s8v*)((const short*)in + i);
#pragma unroll
    for (int j = 0; j < 8; ++j) l[j] = 0;
  }
  *(s8v*)(hi + i) = h;
  *(s8v*)(lo + i) = l;
}

// ---------------- transpose -> hi (+lo) bf16 planes ----------------
// AMODE: 0 = input dtype per flag, 2 = input bf16.  out[c][r] = in[r][c].
template<int AMODE, bool LO>
__global__ __launch_bounds__(256)
void transpose_hl(const int* __restrict__ flg, const void* __restrict__ in_v,
                  u16* __restrict__ outH, u16* __restrict__ outL,
                  int R, int C, long sIn, long sOut)
{
  __shared__ float tile[32][33];
  const bool i32 = (AMODE == 0) && (*flg != 0);
  const u16*   in16 = (const u16*)in_v + (long)blockIdx.z * sIn;
  const float* in32 = (const float*)in_v + (long)blockIdx.z * sIn;
  const int c0 = blockIdx.x * 32, r0 = blockIdx.y * 32;
  const int tx = threadIdx.x, ty = threadIdx.y;   // block (32,8)
  for (int i = ty; i < 32; i += 8) {
    const long idx = (long)(r0 + i) * C + c0 + tx;
    tile[i][tx] = i32 ? in32[idx] : bf2f(in16[idx]);
  }
  __syncthreads();
  for (int i = ty; i < 32; i += 8) {
    const long idx = (long)blockIdx.z * sOut + (long)(c0 + i) * R + r0 + tx;
    const float v = tile[tx][i];
    const u16 h = f2bf(v);
    outH[idx] = h;
    if constexpr (LO) outL[idx] = f2bf(v - bf2f(h));
  }
}

// ---------------- plain bf16 NT GEMM, m97 structure ----------------
// C[m][n] = sum_k A[m][k]*Bt[n][k] (+bias[n]).
// OUT_FLAG: true -> fp32 if *flg else bf16; false -> bf16.
template<bool OUT_FLAG, bool HAS_BIAS>
__global__ __launch_bounds__(256)
void gemm16(const int* __restrict__ flg, const u16* __restrict__ A,
            const u16* __restrict__ Bt, const void* __restrict__ bias,
            void* __restrict__ Cv, int M, int N, int K,
            long sA, long sB, long sC)
{
  __shared__ u16 As[BM * BK];
  __shared__ u16 Bs[BN * BK];

  const int f_in = *flg;
  const int tid = threadIdx.x, lane = tid & 63, wave = tid >> 6;
  const int wm = wave >> 1, wn = wave & 1;
  const int m0 = blockIdx.y * BM, n0 = blockIdx.x * BN;
  const long z = blockIdx.z;
  const u16* Ap = A + z * sA;
  const u16* Bp = Bt + z * sB;

  // staging: 16 chunks of 1KB (8 per tile); wave w -> As chunks w*2,w*2+1 and Bs same
  const int rr  = wave * 32 + (lane >> 2);   // tile row for chunk w*2
  const int cc8 = (lane & 3) * 8;            // col (elems)
  const u16* ga0 = Ap + (long)(m0 + rr) * K + cc8;
  const u16* ga1 = ga0 + 16 * (long)K;
  const u16* gb0 = Bp + (long)(n0 + rr) * K + cc8;
  const u16* gb1 = gb0 + 16 * (long)K;
  u16* la0 = &As[(wave * 2    ) * 512];
  u16* la1 = &As[(wave * 2 + 1) * 512];
  u16* lb0 = &Bs[(wave * 2    ) * 512];
  u16* lb1 = &Bs[(wave * 2 + 1) * 512];

  f4v acc[4][4];
#pragma unroll
  for (int i = 0; i < 4; ++i)
#pragma unroll
    for (int j = 0; j < 4; ++j) acc[i][j] = (f4v){0.f, 0.f, 0.f, 0.f};

  const int fr = lane & 15, fk = (lane >> 4) * 8;
  const int aoff = (wm * 64 + fr) * BK + fk;   // + mi*16*BK
  const int boff = (wn * 64 + fr) * BK + fk;

  for (int kt = 0; kt < K; kt += BK) {
    glds16(ga0, la0); glds16(ga1, la1);
    glds16(gb0, lb0); glds16(gb1, lb1);
    ga0 += BK; ga1 += BK; gb0 += BK; gb1 += BK;
    __syncthreads();

    s8v af[4], bfr[4];
#pragma unroll
    for (int mi = 0; mi < 4; ++mi) af[mi]  = *(const s8v*)&As[aoff + mi * 16 * BK];
#pragma unroll
    for (int ni = 0; ni < 4; ++ni) bfr[ni] = *(const s8v*)&Bs[boff + ni * 16 * BK];
#pragma unroll
    for (int mi = 0; mi < 4; ++mi)
#pragma unroll
      for (int ni = 0; ni < 4; ++ni)
        acc[mi][ni] = __builtin_amdgcn_mfma_f32_16x16x32_bf16(af[mi], bfr[ni], acc[mi][ni], 0, 0, 0);
    __syncthreads();
  }

  // epilogue: C/D layout col=lane&15, row=(lane>>4)*4+reg (m89-verified)
  const int cr = (lane >> 4) * 4, ccl = lane & 15;
  const bool o32 = OUT_FLAG && (f_in != 0);
#pragma unroll
  for (int ni = 0; ni < 4; ++ni) {
    const int gcol = n0 + wn * 64 + ni * 16 + ccl;
    float bv = 0.f;
    if (HAS_BIAS)
      bv = (f_in != 0) ? ((const float*)bias)[gcol] : bf2f(((const u16*)bias)[gcol]);
#pragma unroll
    for (int mi = 0; mi < 4; ++mi)
#pragma unroll
      for (int r = 0; r < 4; ++r) {
        const long grow = (long)(m0 + wm * 64 + mi * 16 + cr + r);
        const float val = acc[mi][ni][r] + bv;
        const long idx = z * sC + grow * N + gcol;
        if (o32) ((float*)Cv)[idx] = val;
        else     ((u16*)Cv)[idx]   = f2bf(val);
      }
  }
}

// ---------------- split-precision NT GEMM from pre-decomposed planes ----------------
// C = (Ah+Al)*(Bh+Bl)^T ~= Ah*Bh + Ah*Bl + Al*Bh  (+bias), ~17-bit mantissa.
// OUT_SPLIT: true -> write hi/lo bf16 planes; false -> write fp32.
template<bool OUT_SPLIT, bool HAS_BIAS>
__global__ __launch_bounds__(256)
void gemm16s(const int* __restrict__ flg,
             const u16* __restrict__ Ah, const u16* __restrict__ Al,
             const u16* __restrict__ Bh, const u16* __restrict__ Bl,
             const void* __restrict__ bias,
             void* __restrict__ outH, u16* __restrict__ outL,
             int M, int N, int K, long sA, long sB, long sC)
{
  __shared__ u16 AsH[BM * BK];
  __shared__ u16 AsL[BM * BK];
  __shared__ u16 BsH[BN * BK];
  __shared__ u16 BsL[BN * BK];

  const int f_in = *flg;
  const int tid = threadIdx.x, lane = tid & 63, wave = tid >> 6;
  const int wm = wave >> 1, wn = wave & 1;
  const int m0 = blockIdx.y * BM, n0 = blockIdx.x * BN;
  const long z = blockIdx.z;

  const int rr  = wave * 32 + (lane >> 2);
  const int cc8 = (lane & 3) * 8;
  const long ofsA0 = (long)(m0 + rr) * K + cc8 + z * sA;
  const long ofsB0 = (long)(n0 + rr) * K + cc8 + z * sB;
  const u16* gah0 = Ah + ofsA0;  const u16* gah1 = gah0 + 16 * (long)K;
  const u16* gal0 = Al + ofsA0;  const u16* gal1 = gal0 + 16 * (long)K;
  const u16* gbh0 = Bh + ofsB0;  const u16* gbh1 = gbh0 + 16 * (long)K;
  const u16* gbl0 = Bl + ofsB0;  const u16* gbl1 = gbl0 + 16 * (long)K;
  u16* lah0 = &AsH[(wave * 2) * 512];  u16* lah1 = lah0 + 512;
  u16* lal0 = &AsL[(wave * 2) * 512];  u16* lal1 = lal0 + 512;
  u16* lbh0 = &BsH[(wave * 2) * 512];  u16* lbh1 = lbh0 + 512;
  u16* lbl0 = &BsL[(wave * 2) * 512];  u16* lbl1 = lbl0 + 512;

  f4v acc[4][4];
#pragma unroll
  for (int i = 0; i < 4; ++i)
#pragma unroll
    for (int j = 0; j < 4; ++j) acc[i][j] = (f4v){0.f, 0.f, 0.f, 0.f};

  const int fr = lane & 15, fk = (lane >> 4) * 8;
  const int aoff = (wm * 64 + fr) * BK + fk;
  const int boff = (wn * 64 + fr) * BK + fk;

  for (int kt = 0; kt < K; kt += BK) {
    glds16(gah0, lah0); glds16(gah1, lah1);
    glds16(gal0, lal0); glds16(gal1, lal1);
    glds16(gbh0, lbh0); glds16(gbh1, lbh1);
    glds16(gbl0, lbl0); glds16(gbl1, lbl1);
    gah0 += BK; gah1 += BK; gal0 += BK; gal1 += BK;
    gbh0 += BK; gbh1 += BK; gbl0 += BK; gbl1 += BK;
    __syncthreads();

    s8v ah[4], al[4], bh[4], bl[4];
#pragma unroll
    for (int mi = 0; mi < 4; ++mi) {
      ah[mi] = *(const s8v*)&AsH[aoff + mi * 16 * BK];
      al[mi] = *(const s8v*)&AsL[aoff + mi * 16 * BK];
    }
#pragma unroll
    for (int ni = 0; ni < 4; ++ni) {
      bh[ni] = *(const s8v*)&BsH[boff + ni * 16 * BK];
      bl[ni] = *(const s8v*)&BsL[boff + ni * 16 * BK];
    }
#pragma unroll
    for (int mi = 0; mi < 4; ++mi)
#pragma unroll
      for (int ni = 0; ni < 4; ++ni) {
        acc[mi][ni] = __builtin_amdgcn_mfma_f32_16x16x32_bf16(ah[mi], bh[ni], acc[mi][ni], 0, 0, 0);
        acc[mi][ni] = __builtin_amdgcn_mfma_f32_16x16x32_bf16(ah[mi], bl[ni], acc[mi][ni], 0, 0, 0);
        acc[mi][ni] = __builtin_amdgcn_mfma_f32_16x16x32_bf16(al[mi], bh[ni], acc[mi][ni], 0, 0, 0);
      }
    __syncthreads();
  }

  const int cr = (lane >> 4) * 4, ccl = lane & 15;
#pragma unroll
  for (int ni = 0; ni < 4; ++ni) {
    const int gcol = n0 + wn * 64 + ni * 16 + ccl;
    float bv = 0.f;
    if (HAS_BIAS)
      bv = (f_in != 0) ? ((const float*)bias)[gcol] : bf2f(((const u16*)bias)[gcol]);
#pragma unroll
    for (int mi = 0; mi < 4; ++mi)
#pragma unroll
      for (int r = 0; r < 4; ++r) {
        const long grow = (long)(m0 + wm * 64 + mi * 16 + cr + r);
        const float val = acc[mi][ni][r] + bv;
        const long idx = z * sC + grow * N + gcol;
        if constexpr (OUT_SPLIT) {
          const u16 h = f2bf(val);
          ((u16*)outH)[idx] = h;
          outL[idx] = f2bf(val - bf2f(h));
        } else {
          ((float*)outH)[idx] = val;
        }
      }
  }
}

// ---------------- row softmax fp32 -> bf16 attn, N=2048, one block/row ----------------
__global__ __launch_bounds__(256)
void softmax_rows_bf(const float* __restrict__ S, u16* __restrict__ P, int N)
{
  const float* row = S + (long)blockIdx.x * N;
  u16* prow = P + (long)blockIdx.x * N;
  const int t = threadIdx.x;
  f4v v0 = *(const f4v*)(row + t * 8);
  f4v v1 = *(const f4v*)(row + t * 8 + 4);

  float m = v0[0];
#pragma unroll
  for (int j = 1; j < 4; ++j) m = fmaxf(m, v0[j]);
#pragma unroll
  for (int j = 0; j < 4; ++j) m = fmaxf(m, v1[j]);
  for (int off = 32; off > 0; off >>= 1) m = fmaxf(m, __shfl_down(m, off, 64));

  __shared__ float redm[4], reds[4];
  if ((t & 63) == 0) redm[t >> 6] = m;
  __syncthreads();
  m = fmaxf(fmaxf(redm[0], redm[1]), fmaxf(redm[2], redm[3]));

  float s = 0.f;
#pragma unroll
  for (int j = 0; j < 4; ++j) { v0[j] = __expf(v0[j] - m); s += v0[j]; }
#pragma unroll
  for (int j = 0; j < 4; ++j) { v1[j] = __expf(v1[j] - m); s += v1[j]; }
  for (int off = 32; off > 0; off >>= 1) s += __shfl_down(s, off, 64);
  if ((t & 63) == 0) reds[t >> 6] = s;
  __syncthreads();
  s = reds[0] + reds[1] + reds[2] + reds[3];

  const float inv = 1.f / s;
  s8v o;
#pragma unroll
  for (int j = 0; j < 4; ++j) {
    o[j]     = (short)f2bf(v0[j] * inv);
    o[4 + j] = (short)f2bf(v1[j] * inv);
  }
  *(s8v*)(prow + t * 8) = o;
}

extern "C" void kernel_launch(void* const* d_in, const int* in_sizes, int n_in,
                              void* d_out, int out_size, void* d_ws, size_t ws_size,
                              hipStream_t stream)
{
  const void* query = d_in[0];
  const void* kv    = d_in[1];
  const void* Wq    = d_in[2];
  const void* bq    = d_in[3];
  const void* Wk    = d_in[4];
  const void* bk    = d_in[5];
  const void* Wv    = d_in[6];
  const void* bv    = d_in[7];
  const void* Wo    = d_in[8];
  const void* bo    = d_in[9];

  const int Bn = 4, S = 2048, D = 1024;
  const int MS = Bn * S;                       // 8192
  const size_t KBu = 1024, MBu = 1024 * 1024;
  const long nTok = (long)MS * D;              // 8388608 elems

  // ---- workspace layout (total ~172.1 MB; overlays verified by stream order) ----
  char* ws = (char*)d_ws;
  int*   flg  = (int*)(ws);
  char*  rA   = ws + 64 * KBu;                 // 64MB region: input planes, later Sc
  u16*   Qih  = (u16*)(rA);                    // 16MB
  u16*   Qil  = (u16*)(rA + 16 * MBu);
  u16*   KVh  = (u16*)(rA + 32 * MBu);
  u16*   KVl  = (u16*)(rA + 48 * MBu);
  float* Sc   = (float*)(rA);                  // 64MB fp32 scores (inputs dead by then)
  char*  rW   = rA + 64 * MBu;                 // 12MB: W^T planes
  u16*   WqTh = (u16*)(rW);
  u16*   WqTl = (u16*)(rW + 2 * MBu);
  u16*   WkTh = (u16*)(rW + 4 * MBu);
  u16*   WkTl = (u16*)(rW + 6 * MBu);
  u16*   WvTh = (u16*)(rW + 8 * MBu);
  u16*   WoTh = (u16*)(rW + 10 * MBu);
  char*  rQK  = rW + 12 * MBu;                 // 64MB: Q/K planes, later attn
  u16*   Qh   = (u16*)(rQK);
  u16*   Ql   = (u16*)(rQK + 16 * MBu);
  u16*   Kh   = (u16*)(rQK + 32 * MBu);
  u16*   Kl   = (u16*)(rQK + 48 * MBu);
  u16*   attn = (u16*)(rQK);                   // 32MB bf16 (Q planes dead after scores)
  char*  rV   = rQK + 64 * MBu;                // 32MB
  u16*   Vb   = (u16*)(rV);                    // 16MB, dead after V^T
  u16*   Cx   = (u16*)(rV);                    // ctx overlays Vb
  u16*   Vt   = (u16*)(rV + 16 * MBu);         // 16MB

  detect_dtype<<<1, 256, 0, stream>>>((const u16*)query, flg);

  // input hi/lo planes
  convert_hl<<<dim3((unsigned)(nTok / 2048)), 256, 0, stream>>>(flg, query, Qih, Qil, nTok);
  convert_hl<<<dim3((unsigned)(nTok / 2048)), 256, 0, stream>>>(flg, kv, KVh, KVl, nTok);

  dim3 tb(32, 8);
  transpose_hl<0, true ><<<dim3(32, 32, 1), tb, 0, stream>>>(flg, Wq, WqTh, WqTl, D, D, 0L, 0L);
  transpose_hl<0, true ><<<dim3(32, 32, 1), tb, 0, stream>>>(flg, Wk, WkTh, WkTl, D, D, 0L, 0L);
  transpose_hl<0, false><<<dim3(32, 32, 1), tb, 0, stream>>>(flg, Wv, WvTh, nullptr, D, D, 0L, 0L);
  transpose_hl<0, false><<<dim3(32, 32, 1), tb, 0, stream>>>(flg, Wo, WoTh, nullptr, D, D, 0L, 0L);

  // projections: Q,K split -> hi/lo planes; V plain -> bf16
  gemm16s<true, true><<<dim3(D / BN, MS / BM, 1), 256, 0, stream>>>(
      flg, Qih, Qil, WqTh, WqTl, bq, Qh, Ql, MS, D, D, 0L, 0L, 0L);
  gemm16s<true, true><<<dim3(D / BN, MS / BM, 1), 256, 0, stream>>>(
      flg, KVh, KVl, WkTh, WkTl, bk, Kh, Kl, MS, D, D, 0L, 0L, 0L);
  gemm16<false, true><<<dim3(D / BN, MS / BM, 1), 256, 0, stream>>>(
      flg, KVh, WvTh, bv, Vb, MS, D, D, 0L, 0L, 0L);

  // V^T per batch: [D][S]
  transpose_hl<2, false><<<dim3(D / 32, S / 32, Bn), tb, 0, stream>>>(
      flg, Vb, Vt, nullptr, S, D, (long)S * D, (long)D * S);

  // scores (split, fp32 out), softmax -> bf16 attn, PV (plain bf16)
  gemm16s<false, false><<<dim3(S / BN, S / BM, Bn), 256, 0, stream>>>(
      flg, Qh, Ql, Kh, Kl, nullptr, Sc, nullptr,
      S, S, D, (long)S * D, (long)S * D, (long)S * S);
  softmax_rows_bf<<<dim3(Bn * S), 256, 0, stream>>>(Sc, attn, S);
  gemm16<false, false><<<dim3(D / BN, S / BM, Bn), 256, 0, stream>>>(
      flg, attn, Vt, nullptr, Cx,
      S, D, S, (long)S * S, (long)D * S, (long)S * D);

  // output projection -> d_out (dtype per flag)
  gemm16<true, true><<<dim3(D / BN, MS / BM, 1), 256, 0, stream>>>(
      flg, Cx, WoTh, bo, d_out, MS, D, D, 0L, 0L, 0L);
}